// Round 6
// baseline (247.351 us; speedup 1.0000x reference)
//
#include <hip/hip_runtime.h>

#define IN_FEAT 1024
#define OUT_FEAT 1024
#define NSAMP 8192
#define KBASE 1024
#define KSPL 8192
// fp6 tiled layout: [rowblk][kb(64)][quad(4)][row(128)][24B]
#define GRANB 24                     /* bytes per 32-elem fp6 granule */
#define KBBYTES (4 * 128 * GRANB)    /* 12288 B: one k-block for 128 rows */
#define RBSTRIDE (64L * KBBYTES)     /* 786432 B per 128-row block */

typedef __bf16 v8bf __attribute__((ext_vector_type(8)));
typedef float v4f __attribute__((ext_vector_type(4)));
typedef int v8i __attribute__((ext_vector_type(8)));
typedef unsigned long long u64;

__device__ __forceinline__ void load16_lds(const void* g, void* l) {
  __builtin_amdgcn_global_load_lds(
      (const __attribute__((address_space(1))) void*)g,
      (__attribute__((address_space(3))) void*)l, 16, 0, 0);
}

// fp6 e2m3 encode (round-nearest): subnorm step .125; 2^(e-1)*(1+m/8); max 7.5
__device__ __forceinline__ unsigned enc_e2m3(float v) {
  unsigned s = 0u;
  float a = v;
  if (a < 0.f) { s = 32u; a = -a; }
  unsigned code;
  if (a < 1.9375f)      code = (unsigned)rintf(a * 8.0f);
  else if (a < 3.875f)  code = 16u + (unsigned)rintf((a - 2.0f) * 4.0f);
  else if (a < 7.25f)   code = 24u + (unsigned)rintf((a - 4.0f) * 2.0f);
  else                  code = 31u;
  return s | code;
}

__device__ __forceinline__ void cox_de_boor(float xv, const float* gv, float* b) {
  float t[11];
#pragma unroll
  for (int j = 0; j < 11; ++j)
    t[j] = (xv >= gv[j] && xv < gv[j + 1]) ? 1.0f : 0.0f;
  const float invh[3] = {2.5f, 1.25f, 0.83333333333333f};
#pragma unroll
  for (int k = 1; k <= 3; ++k) {
    float ik = invh[k - 1];
#pragma unroll
    for (int j = 0; j + k < 11; ++j)
      t[j] = (xv - gv[j]) * ik * t[j] + (gv[j + k + 1] - xv) * ik * t[j + 1];
  }
#pragma unroll
  for (int j = 0; j < 8; ++j) b[j] = t[j];
}

// Granule builder: one thread = one fp6 granule (32 elems = 4 i's x 8 bases).
// A-range blocks [0,8192): bases*4 (scale 2^-2 in MFMA) + fused silu->A1.
// B-range blocks [8192,9216): sw*sc*256 (scale 2^-8) + fused bw->B1.
__global__ __launch_bounds__(256) void build_AB(const float* __restrict__ x,
                                                const float* __restrict__ grid,
                                                const float* __restrict__ bw,
                                                const float* __restrict__ sw,
                                                const float* __restrict__ sc,
                                                __bf16* __restrict__ A1,
                                                unsigned char* __restrict__ A2,
                                                __bf16* __restrict__ B1,
                                                unsigned char* __restrict__ B2) {
  u64 w0 = 0, w1 = 0, w2 = 0;
  unsigned code[32];
  unsigned char* dst;

  if (blockIdx.x < 8192) {
    int g = blockIdx.x * 256 + threadIdx.x;      // 2,097,152 A-granules
    int r = g & 127;
    int quad = (g >> 7) & 3;
    int kb = (g >> 9) & 63;
    int rb = g >> 15;
    long n = rb * 128 + r;
    int i0 = kb * 16 + quad * 4;

    float gv[12];
#pragma unroll
    for (int t = 0; t < 12; ++t) gv[t] = grid[t]; // identical rows -> row 0

    float4 xv4 = *reinterpret_cast<const float4*>(x + n * IN_FEAT + i0);
    float xs[4] = {xv4.x, xv4.y, xv4.z, xv4.w};

    // fused silu -> A1 (4 bf16, 8B store)
    union { __bf16 h[4]; u64 u; } a1;
#pragma unroll
    for (int j = 0; j < 4; ++j)
      a1.h[j] = (__bf16)(xs[j] / (1.0f + __expf(-xs[j])));
    *reinterpret_cast<u64*>(A1 + n * IN_FEAT + i0) = a1.u;

#pragma unroll
    for (int j = 0; j < 4; ++j) {
      float b[8];
      cox_de_boor(xs[j], gv, b);
#pragma unroll
      for (int kk = 0; kk < 8; ++kk)
        code[j * 8 + kk] = enc_e2m3(b[kk] * 4.0f); // prescale 4 = 2^2
    }
    dst = A2 + rb * RBSTRIDE + kb * KBBYTES + quad * (128 * GRANB) + r * GRANB;
  } else {
    int g = (blockIdx.x - 8192) * 256 + threadIdx.x; // 262,144 B-granules
    int r = g & 127;
    int quad = (g >> 7) & 3;
    int kb = (g >> 9) & 63;
    int ob = g >> 15;
    long o = ob * 128 + r;
    int i0 = kb * 16 + quad * 4;

    float4 bw4 = *reinterpret_cast<const float4*>(bw + o * IN_FEAT + i0);
    float bws[4] = {bw4.x, bw4.y, bw4.z, bw4.w};
    union { __bf16 h[4]; u64 u; } b1;
#pragma unroll
    for (int j = 0; j < 4; ++j) b1.h[j] = (__bf16)bws[j];
    *reinterpret_cast<u64*>(B1 + o * IN_FEAT + i0) = b1.u;

    float4 sc4 = *reinterpret_cast<const float4*>(sc + o * IN_FEAT + i0);
    float scs[4] = {sc4.x, sc4.y, sc4.z, sc4.w};
#pragma unroll
    for (int j = 0; j < 4; ++j) {
      float scale = scs[j] * 256.0f; // 2^8, undone by scaleB=119
      const float4* sp =
          reinterpret_cast<const float4*>(sw + (o * IN_FEAT + i0 + j) * 8);
      float4 p0 = sp[0];
      float4 p1 = sp[1];
      float wv[8] = {p0.x, p0.y, p0.z, p0.w, p1.x, p1.y, p1.z, p1.w};
#pragma unroll
      for (int kk = 0; kk < 8; ++kk)
        code[j * 8 + kk] = enc_e2m3(wv[kk] * scale);
    }
    dst = B2 + (long)ob * RBSTRIDE + kb * KBBYTES + quad * (128 * GRANB) + r * GRANB;
  }

  // pack 32x 6-bit codes little-endian into 192 bits
#pragma unroll
  for (int e = 0; e < 32; ++e) {
    u64 c = code[e];
    int bp = 6 * e;
    if (bp < 64) {
      w0 |= c << bp;
      if (bp > 58) w1 |= c >> (64 - bp);
    } else if (bp < 128) {
      w1 |= c << (bp - 64);
      if (bp > 122) w2 |= c >> (128 - bp);
    } else {
      w2 |= c << (bp - 128);
    }
  }
  u64* dq = reinterpret_cast<u64*>(dst); // 8-aligned (24|3072|12288|RBSTRIDE)
  dq[0] = w0;
  dq[1] = w1;
  dq[2] = w2;
}

// Fused: C = spline (MX-fp6 16x16x128, K=8192, scales fold the prescales)
//          + base  (bf16 16x16x32, K=1024). Single C write.
__global__ __launch_bounds__(256, 2) void gemm_fused(const unsigned char* __restrict__ A2,
                                                     const unsigned char* __restrict__ B2,
                                                     const __bf16* __restrict__ A1,
                                                     const __bf16* __restrict__ B1,
                                                     float* __restrict__ C) {
  __shared__ __attribute__((aligned(16))) unsigned char smem[24576];
  const int tid = threadIdx.x;
  const int bm = blockIdx.x;
  const int bn = blockIdx.y;

  const int lane = tid & 63;
  const int w = tid >> 6;
  const int wm = (w >> 1) * 64;
  const int wn = (w & 1) * 64;
  const int l16 = lane & 15;
  const int quad = lane >> 4;

  v4f acc[4][4] = {};

  // ---------------- Phase 1: fp6 MX, K=8192, BK=128 ----------------
  {
    unsigned char* As = smem;          // 12 KB, layout [quad][row][24B]
    unsigned char* Bs = smem + 12288;  // 12 KB
    const unsigned char* gA[3];
    const unsigned char* gB[3];
    unsigned char* lA[3];
    unsigned char* lB[3];
#pragma unroll
    for (int t = 0; t < 3; ++t) {
      int c = tid + t * 256; // 768 chunks = linear 12KB tile copy
      gA[t] = A2 + (long)bm * RBSTRIDE + c * 16;
      gB[t] = B2 + (long)bn * RBSTRIDE + c * 16;
      lA[t] = &As[c * 16];
      lB[t] = &Bs[c * 16];
    }
    const int foff = quad * (128 * GRANB) + l16 * GRANB; // + mi*16*GRANB

    for (long off = 0; off < 64L * KBBYTES; off += KBBYTES) {
#pragma unroll
      for (int t = 0; t < 3; ++t) load16_lds(gA[t] + off, lA[t]);
#pragma unroll
      for (int t = 0; t < 3; ++t) load16_lds(gB[t] + off, lB[t]);
      __syncthreads();

      v8i af[4], bfr[4];
#pragma unroll
      for (int mi = 0; mi < 4; ++mi) {
        const unsigned char* rb = &As[(wm + mi * 16) * GRANB + foff];
        u64 a0 = *reinterpret_cast<const u64*>(rb);
        u64 a1 = *reinterpret_cast<const u64*>(rb + 8);
        u64 a2 = *reinterpret_cast<const u64*>(rb + 16);
        v8i f = {(int)a0, (int)(a0 >> 32), (int)a1, (int)(a1 >> 32),
                 (int)a2, (int)(a2 >> 32), 0, 0};
        af[mi] = f;
      }
#pragma unroll
      for (int ni = 0; ni < 4; ++ni) {
        const unsigned char* rb = &Bs[(wn + ni * 16) * GRANB + foff];
        u64 b0 = *reinterpret_cast<const u64*>(rb);
        u64 b1 = *reinterpret_cast<const u64*>(rb + 8);
        u64 b2 = *reinterpret_cast<const u64*>(rb + 16);
        v8i f = {(int)b0, (int)(b0 >> 32), (int)b1, (int)(b1 >> 32),
                 (int)b2, (int)(b2 >> 32), 0, 0};
        bfr[ni] = f;
      }
#pragma unroll
      for (int mi = 0; mi < 4; ++mi)
#pragma unroll
        for (int ni = 0; ni < 4; ++ni)
          // fmt 2 = fp6 e2m3 both; scaleA=125 (2^-2), scaleB=119 (2^-8)
          acc[mi][ni] = __builtin_amdgcn_mfma_scale_f32_16x16x128_f8f6f4(
              af[mi], bfr[ni], acc[mi][ni], 2, 2, 0, 125, 0, 119);
      __syncthreads();
    }
  }

  // ---------------- Phase 2: bf16, K=1024, BK=32 ----------------
  {
    __bf16* As = reinterpret_cast<__bf16*>(smem);        // 8 KB
    __bf16* Bs = reinterpret_cast<__bf16*>(smem + 8192); // 8 KB
    const int c0 = tid, c1 = tid + 256;
    const __bf16* gA0 = A1 + (long)(bm * 128 + (c0 >> 2)) * KBASE + (c0 & 3) * 8;
    const __bf16* gA1 = A1 + (long)(bm * 128 + (c1 >> 2)) * KBASE + (c1 & 3) * 8;
    const __bf16* gB0 = B1 + (long)(bn * 128 + (c0 >> 2)) * KBASE + (c0 & 3) * 8;
    const __bf16* gB1 = B1 + (long)(bn * 128 + (c1 >> 2)) * KBASE + (c1 & 3) * 8;
    __bf16* lA0 = &As[c0 * 8];
    __bf16* lA1 = &As[c1 * 8];
    __bf16* lB0 = &Bs[c0 * 8];
    __bf16* lB1 = &Bs[c1 * 8];
    const __bf16* aF = &As[(wm + l16) * 32 + quad * 8];
    const __bf16* bF = &Bs[(wn + l16) * 32 + quad * 8];

    for (int k0 = 0; k0 < KBASE; k0 += 32) {
      load16_lds(gA0 + k0, lA0);
      load16_lds(gA1 + k0, lA1);
      load16_lds(gB0 + k0, lB0);
      load16_lds(gB1 + k0, lB1);
      __syncthreads();
      v8bf af[4], bfr[4];
#pragma unroll
      for (int t = 0; t < 4; ++t)
        af[t] = *reinterpret_cast<const v8bf*>(aF + t * 16 * 32);
#pragma unroll
      for (int t = 0; t < 4; ++t)
        bfr[t] = *reinterpret_cast<const v8bf*>(bF + t * 16 * 32);
#pragma unroll
      for (int mi = 0; mi < 4; ++mi)
#pragma unroll
        for (int ni = 0; ni < 4; ++ni)
          acc[mi][ni] = __builtin_amdgcn_mfma_f32_16x16x32_bf16(
              af[mi], bfr[ni], acc[mi][ni], 0, 0, 0);
      __syncthreads();
    }
  }

  // Epilogue: C/D layout col = lane&15, row = quad*4 + reg. Single write.
#pragma unroll
  for (int mi = 0; mi < 4; ++mi)
#pragma unroll
    for (int ni = 0; ni < 4; ++ni)
#pragma unroll
      for (int r = 0; r < 4; ++r) {
        int row = bm * 128 + wm + mi * 16 + quad * 4 + r;
        int col = bn * 128 + wn + ni * 16 + l16;
        C[(long)row * OUT_FEAT + col] = acc[mi][ni][r];
      }
}

extern "C" void kernel_launch(void* const* d_in, const int* in_sizes, int n_in,
                              void* d_out, int out_size, void* d_ws, size_t ws_size,
                              hipStream_t stream) {
  const float* x = (const float*)d_in[0];
  const float* bw = (const float*)d_in[1];
  const float* sw = (const float*)d_in[2];
  const float* sc = (const float*)d_in[3];
  const float* grid = (const float*)d_in[4];
  float* out = (float*)d_out;

  // ws: A1 bf16 16.8MB | A2 fp6 50.3MB | B1 bf16 2MB | B2 fp6 6.3MB
  __bf16* A1 = (__bf16*)d_ws;
  unsigned char* A2 = (unsigned char*)(A1 + (size_t)NSAMP * KBASE);
  __bf16* B1 = (__bf16*)(A2 + 64L * RBSTRIDE);
  unsigned char* B2 = (unsigned char*)(B1 + (size_t)OUT_FEAT * KBASE);

  build_AB<<<8192 + 1024, 256, 0, stream>>>(x, grid, bw, sw, sc, A1, A2, B1, B2);
  gemm_fused<<<dim3(NSAMP / 128, OUT_FEAT / 128), 256, 0, stream>>>(
      A2, B2, A1, B1, out);
}